// Round 10
// baseline (381.674 us; speedup 1.0000x reference)
//
#include <hip/hip_runtime.h>
#include <hip/hip_bf16.h>
#include <math.h>

static inline size_t align_up(size_t x, size_t a) { return (x + a - 1) / a * a; }

typedef short bf16x8 __attribute__((ext_vector_type(8)));
typedef float f32x4 __attribute__((ext_vector_type(4)));
typedef unsigned short u16x8 __attribute__((ext_vector_type(8)));
typedef int i32x4 __attribute__((ext_vector_type(4)));

// ---------------- CSR build ----------------

__global__ void hist_kernel(const int* __restrict__ dst, int* __restrict__ cnt, int e) {
  int i = blockIdx.x * blockDim.x + threadIdx.x;
  if (i < e) atomicAdd(&cnt[dst[i]], 1);
}

__global__ __launch_bounds__(256) void scanA_kernel(const int* __restrict__ cnt,
                                                    int* __restrict__ excl,
                                                    int* __restrict__ bsum, int n) {
  __shared__ int sm[256];
  int gi = blockIdx.x * 256 + threadIdx.x;
  int v = (gi < n) ? cnt[gi] : 0;
  sm[threadIdx.x] = v;
  __syncthreads();
  for (int off = 1; off < 256; off <<= 1) {
    int x = (threadIdx.x >= off) ? sm[threadIdx.x - off] : 0;
    __syncthreads();
    sm[threadIdx.x] += x;
    __syncthreads();
  }
  if (gi < n) excl[gi] = sm[threadIdx.x] - v;
  if (threadIdx.x == 255) bsum[blockIdx.x] = sm[255];
}

__global__ __launch_bounds__(512) void scanB_kernel(int* __restrict__ bsum, int nb) {
  __shared__ int sm[512];
  const int t = threadIdx.x;
  int v = (t < nb) ? bsum[t] : 0;
  sm[t] = v;
  __syncthreads();
  for (int off = 1; off < 512; off <<= 1) {
    int x = (t >= off) ? sm[t - off] : 0;
    __syncthreads();
    sm[t] += x;
    __syncthreads();
  }
  if (t < nb) bsum[t] = sm[t] - v;  // exclusive block offsets
}

// rowptr finalize + dinv from counts (cnt still holds per-node degree here)
__global__ void scanC_dinv_kernel(int* __restrict__ rowptr, const int* __restrict__ bsum,
                                  const int* __restrict__ cnt, float* __restrict__ dinv,
                                  int n, int e) {
  int gi = blockIdx.x * 256 + threadIdx.x;
  if (gi < n) {
    rowptr[gi] += bsum[blockIdx.x];
    dinv[gi] = rsqrtf((float)(cnt[gi] + 1));
  }
  if (gi == 0) rowptr[n] = e;
}

// ---------------- fill: XCD-range-filtered, nt-streamed, 4B records ----------------
// Block (xcd=bid&7, chunk=bid>>3) nt-streams its 4096-edge chunk, keeps edges with
// dst in the xcd's node range. esrc slice/XCD = ~800KB (L2-resident); nt loads keep
// the streams from evicting dirty partial lines -> full-line evictions only.

__global__ __launch_bounds__(256) void fill_xcd_kernel(
    const int* __restrict__ src, const int* __restrict__ dst,
    const int* __restrict__ rowptr, int* __restrict__ cnt,
    int* __restrict__ esrc, int E, int N, int NR) {
  const int xcd = blockIdx.x & 7;
  const int chunk = blockIdx.x >> 3;
  const int lo = xcd * NR;
  const int hi = min(lo + NR, N);
  const int base = chunk * 4096;
#pragma unroll
  for (int j = 0; j < 4; ++j) {
    const int idx = base + j * 1024 + threadIdx.x * 4;
    if (idx < E) {
      const i32x4 d4 = __builtin_nontemporal_load((const i32x4*)(dst + idx));
      const i32x4 s4 = __builtin_nontemporal_load((const i32x4*)(src + idx));
#pragma unroll
      for (int c = 0; c < 4; ++c) {
        const int d = d4[c];
        if (d >= lo && d < hi) {
          const int old = atomicSub(&cnt[d], 1);
          const int pos = rowptr[d] + old - 1;
          esrc[pos] = s4[c];
        }
      }
    }
  }
}

// ---------------- split-bf16 helpers ----------------

__device__ __forceinline__ void bf16_split(float x, unsigned short& hi, unsigned short& lo) {
  unsigned u = __float_as_uint(x);
  unsigned r = (u + 0x7fffu + ((u >> 16) & 1u)) & 0xffff0000u;
  hi = (unsigned short)(r >> 16);
  float rem = x - __uint_as_float(r);
  unsigned u2 = __float_as_uint(rem);
  unsigned r2 = u2 + 0x7fffu + ((u2 >> 16) & 1u);
  lo = (unsigned short)(r2 >> 16);
}

__device__ __forceinline__ unsigned short bf16_rtn(float x) {
  unsigned u = __float_as_uint(x);
  return (unsigned short)((u + 0x7fffu + ((u >> 16) & 1u)) >> 16);
}

// Pack both weight matrices into MFMA B-fragment order, split hi/lo bf16.
// Entry (k,n): flat = (((k>>5)*128 + n)*4 + ((k>>3)&3))*8 + (k&7)
__global__ void wsplit_kernel(const float* __restrict__ W1, const float* __restrict__ W2,
                              unsigned short* __restrict__ w1hi, unsigned short* __restrict__ w1lo,
                              unsigned short* __restrict__ w2hi, unsigned short* __restrict__ w2lo) {
  int i = blockIdx.x * blockDim.x + threadIdx.x;
  const int t1 = 160 * 128;
  const int t2 = 128 * 128;
  const float* W;
  unsigned short *whi, *wlo;
  if (i < t1) {
    W = W1; whi = w1hi; wlo = w1lo;
  } else {
    i -= t1;
    if (i >= t2) return;
    W = W2; whi = w2hi; wlo = w2lo;
  }
  int k = i >> 7;
  int n = i & 127;
  unsigned short h, l;
  bf16_split(W[i], h, l);
  size_t idx = ((size_t)(((k >> 5) * 128 + n) * 4 + ((k >> 3) & 3)) << 3) + (k & 7);
  whi[idx] = h;
  wlo[idx] = l;
}

// ---------------- GEMM (layer 1): fp32 A (x|emb concat) -> bf16 out ----------------

__global__ __launch_bounds__(512) void gemm_mfma_kernel(
    const float* __restrict__ A, const float* __restrict__ emb,
    const int* __restrict__ drnl,
    const unsigned short* __restrict__ whi, const unsigned short* __restrict__ wlo,
    unsigned short* __restrict__ outb, int n, int K) {
  __shared__ unsigned short smem[16896];  // B tile hi|lo; epilogue: [128][132] transpose
  const int tid = threadIdx.x;
  const int row0 = blockIdx.x * 128;
  const int w = tid >> 6;
  const int l = tid & 63;
  const int r = l & 15;
  const int q = l >> 4;
  const int grow = row0 + (w << 4) + r;
  const bool rowok = grow < n;
  const int nks = K >> 5;

  int embrow = 0;
  if (K > 128 && rowok) embrow = drnl[grow];

  f32x4 acc[8];
#pragma unroll
  for (int ct = 0; ct < 8; ++ct) {
    acc[ct][0] = 0.f; acc[ct][1] = 0.f; acc[ct][2] = 0.f; acc[ct][3] = 0.f;
  }

  u16x8 bst_h = *(const u16x8*)(whi + (size_t)tid * 8);
  u16x8 bst_l = *(const u16x8*)(wlo + (size_t)tid * 8);

  for (int ks = 0; ks < nks; ++ks) {
    const int k0 = (ks << 5) + (q << 3);
    float4 a0 = make_float4(0.f, 0.f, 0.f, 0.f), a1 = a0;
    if (rowok) {
      if (k0 < 128) {
        const float* ap = A + (size_t)grow * 128 + k0;
        a0 = *(const float4*)ap;
        a1 = *(const float4*)(ap + 4);
      } else {
        const float* ep = emb + (size_t)embrow * 32 + (k0 - 128);
        a0 = *(const float4*)ep;
        a1 = *(const float4*)(ep + 4);
      }
    }
    bf16x8 ah, al;
    {
      unsigned short h, lo_;
      bf16_split(a0.x, h, lo_); ah[0] = (short)h; al[0] = (short)lo_;
      bf16_split(a0.y, h, lo_); ah[1] = (short)h; al[1] = (short)lo_;
      bf16_split(a0.z, h, lo_); ah[2] = (short)h; al[2] = (short)lo_;
      bf16_split(a0.w, h, lo_); ah[3] = (short)h; al[3] = (short)lo_;
      bf16_split(a1.x, h, lo_); ah[4] = (short)h; al[4] = (short)lo_;
      bf16_split(a1.y, h, lo_); ah[5] = (short)h; al[5] = (short)lo_;
      bf16_split(a1.z, h, lo_); ah[6] = (short)h; al[6] = (short)lo_;
      bf16_split(a1.w, h, lo_); ah[7] = (short)h; al[7] = (short)lo_;
    }

    if (ks) __syncthreads();
    *(u16x8*)&smem[tid * 8] = bst_h;
    *(u16x8*)&smem[4096 + tid * 8] = bst_l;
    __syncthreads();

    if (ks + 1 < nks) {
      bst_h = *(const u16x8*)(whi + (size_t)(ks + 1) * 4096 + (size_t)tid * 8);
      bst_l = *(const u16x8*)(wlo + (size_t)(ks + 1) * 4096 + (size_t)tid * 8);
    }

#pragma unroll
    for (int ct = 0; ct < 8; ++ct) {
      const int boff = ((ct << 4) + r) * 32 + (q << 3);
      const bf16x8 bh = *(const bf16x8*)&smem[boff];
      const bf16x8 bl = *(const bf16x8*)&smem[4096 + boff];
      acc[ct] = __builtin_amdgcn_mfma_f32_16x16x32_bf16(ah, bh, acc[ct], 0, 0, 0);
      acc[ct] = __builtin_amdgcn_mfma_f32_16x16x32_bf16(al, bh, acc[ct], 0, 0, 0);
      acc[ct] = __builtin_amdgcn_mfma_f32_16x16x32_bf16(ah, bl, acc[ct], 0, 0, 0);
    }
  }

  __syncthreads();
#pragma unroll
  for (int ct = 0; ct < 8; ++ct) {
    const int col = (ct << 4) + r;
#pragma unroll
    for (int j = 0; j < 4; ++j) {
      const int row = (w << 4) + (q << 2) + j;
      smem[row * 132 + col] = bf16_rtn(acc[ct][j]);
    }
  }
  __syncthreads();
#pragma unroll
  for (int p = 0; p < 4; ++p) {
    const int idx = p * 512 + tid;
    const int row = idx >> 4;
    const int c8 = (idx & 15) * 8;
    const int gr = row0 + row;
    if (gr < n) {
      u16x8 v = *(const u16x8*)&smem[row * 132 + c8];
      *(u16x8*)(outb + (size_t)gr * 128 + c8) = v;
    }
  }
}

// ---------------- GEMM (layer 2): bf16 A -> bf16 out; 2 MFMAs/step ----------------

__global__ __launch_bounds__(512) void gemm_bf16a_kernel(
    const unsigned short* __restrict__ Ab,
    const unsigned short* __restrict__ whi, const unsigned short* __restrict__ wlo,
    unsigned short* __restrict__ outb, int n) {
  __shared__ unsigned short smem[16896];
  const int tid = threadIdx.x;
  const int row0 = blockIdx.x * 128;
  const int w = tid >> 6;
  const int l = tid & 63;
  const int r = l & 15;
  const int q = l >> 4;
  const int grow = row0 + (w << 4) + r;
  const bool rowok = grow < n;
  const int nks = 4;  // K=128

  f32x4 acc[8];
#pragma unroll
  for (int ct = 0; ct < 8; ++ct) {
    acc[ct][0] = 0.f; acc[ct][1] = 0.f; acc[ct][2] = 0.f; acc[ct][3] = 0.f;
  }

  u16x8 bst_h = *(const u16x8*)(whi + (size_t)tid * 8);
  u16x8 bst_l = *(const u16x8*)(wlo + (size_t)tid * 8);

  for (int ks = 0; ks < nks; ++ks) {
    const int k0 = (ks << 5) + (q << 3);
    bf16x8 ah = {0,0,0,0,0,0,0,0};
    if (rowok) ah = *(const bf16x8*)(Ab + (size_t)grow * 128 + k0);

    if (ks) __syncthreads();
    *(u16x8*)&smem[tid * 8] = bst_h;
    *(u16x8*)&smem[4096 + tid * 8] = bst_l;
    __syncthreads();

    if (ks + 1 < nks) {
      bst_h = *(const u16x8*)(whi + (size_t)(ks + 1) * 4096 + (size_t)tid * 8);
      bst_l = *(const u16x8*)(wlo + (size_t)(ks + 1) * 4096 + (size_t)tid * 8);
    }

#pragma unroll
    for (int ct = 0; ct < 8; ++ct) {
      const int boff = ((ct << 4) + r) * 32 + (q << 3);
      const bf16x8 bh = *(const bf16x8*)&smem[boff];
      const bf16x8 bl = *(const bf16x8*)&smem[4096 + boff];
      acc[ct] = __builtin_amdgcn_mfma_f32_16x16x32_bf16(ah, bh, acc[ct], 0, 0, 0);
      acc[ct] = __builtin_amdgcn_mfma_f32_16x16x32_bf16(ah, bl, acc[ct], 0, 0, 0);
    }
  }

  __syncthreads();
#pragma unroll
  for (int ct = 0; ct < 8; ++ct) {
    const int col = (ct << 4) + r;
#pragma unroll
    for (int j = 0; j < 4; ++j) {
      const int row = (w << 4) + (q << 2) + j;
      smem[row * 132 + col] = bf16_rtn(acc[ct][j]);
    }
  }
  __syncthreads();
#pragma unroll
  for (int p = 0; p < 4; ++p) {
    const int idx = p * 512 + tid;
    const int row = idx >> 4;
    const int c8 = (idx & 15) * 8;
    const int gr = row0 + row;
    if (gr < n) {
      u16x8 v = *(const u16x8*)&smem[row * 132 + c8];
      *(u16x8*)(outb + (size_t)gr * 128 + c8) = v;
    }
  }
}

// ---------------- Aggregation: one wave per node, bf16 gather table ----------------
// esrc: 4B records (wave-uniform broadcast loads); wnorm recomputed from dinv
// (dinv[s] is also a wave-uniform broadcast, L2-resident 400KB table).
// obf16: layer-1 writes bf16 z (feeds gemm2); layer-2 writes fp32 z (head).

__global__ __launch_bounds__(256) void agg_kernel(
    const unsigned* __restrict__ hwb, const int* __restrict__ rowptr,
    const int* __restrict__ esrc, const float* __restrict__ dinv,
    const float* __restrict__ bias, float* __restrict__ zf,
    unsigned* __restrict__ zb, int n, int obf16) {
  const int widx = (blockIdx.x * blockDim.x + threadIdx.x) >> 6;
  if (widx >= n) return;
  const int wid = __builtin_amdgcn_readfirstlane(widx);
  const int lane = threadIdx.x & 63;
  const int start = rowptr[wid];
  const int end = rowptr[wid + 1];
  const float dn = dinv[wid];
  float ax = 0.f, ay = 0.f;
  int e = start;
  for (; e + 4 <= end; e += 4) {
    const int s0 = esrc[e + 0];
    const int s1 = esrc[e + 1];
    const int s2 = esrc[e + 2];
    const int s3 = esrc[e + 3];
    const float d0 = dinv[s0];
    const float d1 = dinv[s1];
    const float d2 = dinv[s2];
    const float d3 = dinv[s3];
    const unsigned u0 = hwb[(size_t)s0 * 64 + lane];
    const unsigned u1 = hwb[(size_t)s1 * 64 + lane];
    const unsigned u2 = hwb[(size_t)s2 * 64 + lane];
    const unsigned u3 = hwb[(size_t)s3 * 64 + lane];
    const float w0 = d0 * dn;
    const float w1 = d1 * dn;
    const float w2 = d2 * dn;
    const float w3 = d3 * dn;
    ax = fmaf(__uint_as_float(u0 << 16), w0, ax);
    ay = fmaf(__uint_as_float(u0 & 0xffff0000u), w0, ay);
    ax = fmaf(__uint_as_float(u1 << 16), w1, ax);
    ay = fmaf(__uint_as_float(u1 & 0xffff0000u), w1, ay);
    ax = fmaf(__uint_as_float(u2 << 16), w2, ax);
    ay = fmaf(__uint_as_float(u2 & 0xffff0000u), w2, ay);
    ax = fmaf(__uint_as_float(u3 << 16), w3, ax);
    ay = fmaf(__uint_as_float(u3 & 0xffff0000u), w3, ay);
  }
  for (; e < end; ++e) {
    const int s0 = esrc[e];
    const float w0 = dinv[s0] * dn;
    const unsigned u0 = hwb[(size_t)s0 * 64 + lane];
    ax = fmaf(__uint_as_float(u0 << 16), w0, ax);
    ay = fmaf(__uint_as_float(u0 & 0xffff0000u), w0, ay);
  }
  const float sw = dn * dn;
  const unsigned us = hwb[(size_t)wid * 64 + lane];
  ax = fmaf(__uint_as_float(us << 16), sw, ax);
  ay = fmaf(__uint_as_float(us & 0xffff0000u), sw, ay);
  const float2 bb = ((const float2*)bias)[lane];
  float ox = ax + bb.x, oy = ay + bb.y;
  ox = ox > 0.f ? ox : 0.f;
  oy = oy > 0.f ? oy : 0.f;
  if (obf16) {
    const unsigned pw = ((unsigned)bf16_rtn(oy) << 16) | (unsigned)bf16_rtn(ox);
    zb[(size_t)wid * 64 + lane] = pw;
  } else {
    float2 o; o.x = ox; o.y = oy;
    ((float2*)zf)[(size_t)wid * 64 + lane] = o;
  }
}

// ---------------- Head: fused segment-max pool + MLP, one block per graph ----------------

__global__ __launch_bounds__(128) void final_kernel(
    const float* __restrict__ z, const int* __restrict__ tloc,
    const int* __restrict__ ptr,
    const float* __restrict__ Wm1, const float* __restrict__ bm1,
    const float* __restrict__ Wm2, const float* __restrict__ bm2,
    float* __restrict__ out, int npg) {
  __shared__ float feats[640];
  __shared__ float hid[128];
  const int g = blockIdx.x;
  const int t = threadIdx.x;
  const float* zbk = z + (size_t)g * npg * 128;
  float m = -INFINITY;
  for (int r = 0; r < npg; ++r) m = fmaxf(m, zbk[(size_t)r * 128 + t]);
  feats[512 + t] = m;
  const int base = ptr[g];
  const int u = base + tloc[2 * g];
  const int v = base + tloc[2 * g + 1];
  const float hu = z[(size_t)u * 128 + t];
  const float hv = z[(size_t)v * 128 + t];
  feats[t] = hu;
  feats[128 + t] = hv;
  feats[256 + t] = fabsf(hu - hv);
  feats[384 + t] = hu * hv;
  __syncthreads();
  float acc = bm1[t];
#pragma unroll 8
  for (int k = 0; k < 640; ++k) acc = fmaf(feats[k], Wm1[(size_t)k * 128 + t], acc);
  hid[t] = acc > 0.f ? acc : 0.f;
  __syncthreads();
  if (t < 2) {
    float a = bm2[t];
    for (int j = 0; j < 128; ++j) a = fmaf(hid[j], Wm2[j * 2 + t], a);
    out[g * 2 + t] = a;
  }
}

// ---------------- launch ----------------

extern "C" void kernel_launch(void* const* d_in, const int* in_sizes, int n_in,
                              void* d_out, int out_size, void* d_ws, size_t ws_size,
                              hipStream_t stream) {
  const float* x   = (const float*)d_in[0];
  const float* emb = (const float*)d_in[1];
  const float* W1  = (const float*)d_in[2];
  const float* b1  = (const float*)d_in[3];
  const float* W2  = (const float*)d_in[4];
  const float* b2  = (const float*)d_in[5];
  const float* Wm1 = (const float*)d_in[6];
  const float* bm1 = (const float*)d_in[7];
  const float* Wm2 = (const float*)d_in[8];
  const float* bm2 = (const float*)d_in[9];
  const int* eidx  = (const int*)d_in[10];
  const int* drnl  = (const int*)d_in[11];
  const int* tloc  = (const int*)d_in[13];
  const int* ptr   = (const int*)d_in[14];
  float* out = (float*)d_out;

  const int N = in_sizes[11];
  const int E = in_sizes[10] / 2;
  const int G = in_sizes[13] / 2;
  const int NPG = N / G;
  const int* srcp = eidx;
  const int* dstp = eidx + E;

  char* w = (char*)d_ws;
  size_t o = 0;
  auto alloc = [&](size_t bytes) {
    void* p = w + o;
    o = align_up(o + bytes, 256);
    return p;
  };
  int*   rowptr = (int*)alloc((size_t)(N + 1) * 4);
  int*   cnt    = (int*)alloc((size_t)N * 4);
  int*   bsum   = (int*)alloc(4096);
  float* dinv   = (float*)alloc((size_t)N * 4);
  int*   esrc   = (int*)alloc((size_t)E * 4);
  unsigned short* hwb = (unsigned short*)alloc((size_t)N * 128 * 2);   // bf16 [N][128]
  unsigned short* zb16 = (unsigned short*)alloc((size_t)N * 128 * 2);  // bf16 z (layer1)
  float* z      = (float*)alloc((size_t)N * 128 * 4);                  // fp32 z (layer2)
  unsigned short* w1hi = (unsigned short*)alloc((size_t)160 * 128 * 2);
  unsigned short* w1lo = (unsigned short*)alloc((size_t)160 * 128 * 2);
  unsigned short* w2hi = (unsigned short*)alloc((size_t)128 * 128 * 2);
  unsigned short* w2lo = (unsigned short*)alloc((size_t)128 * 128 * 2);

  const int nbN = (N + 255) / 256;
  const int nbE = (E + 255) / 256;
  const int nchF = (E + 4095) / 4096;

  hipMemsetAsync(cnt, 0, (size_t)N * 4, stream);
  hist_kernel<<<nbE, 256, 0, stream>>>(dstp, cnt, E);
  scanA_kernel<<<nbN, 256, 0, stream>>>(cnt, rowptr, bsum, N);
  scanB_kernel<<<1, 512, 0, stream>>>(bsum, nbN);
  scanC_dinv_kernel<<<nbN, 256, 0, stream>>>(rowptr, bsum, cnt, dinv, N, E);
  fill_xcd_kernel<<<8 * nchF, 256, 0, stream>>>(srcp, dstp, rowptr, cnt, esrc,
                                                E, N, (N + 7) / 8);

  wsplit_kernel<<<(160 * 128 + 128 * 128 + 255) / 256, 256, 0, stream>>>(
      W1, W2, w1hi, w1lo, w2hi, w2lo);

  gemm_mfma_kernel<<<(N + 127) / 128, 512, 0, stream>>>(x, emb, drnl, w1hi, w1lo, hwb, N, 160);
  agg_kernel<<<(N * 64 + 255) / 256, 256, 0, stream>>>((const unsigned*)hwb, rowptr, esrc,
                                                       dinv, b1, nullptr, (unsigned*)zb16, N, 1);
  gemm_bf16a_kernel<<<(N + 127) / 128, 512, 0, stream>>>(zb16, w2hi, w2lo, hwb, N);
  agg_kernel<<<(N * 64 + 255) / 256, 256, 0, stream>>>((const unsigned*)hwb, rowptr, esrc,
                                                       dinv, b2, z, nullptr, N, 0);
  final_kernel<<<G, 128, 0, stream>>>(z, tloc, ptr, Wm1, bm1, Wm2, bm2, out, NPG);
}

// Round 11
// 277.330 us; speedup vs baseline: 1.3762x; 1.3762x over previous
//
#include <hip/hip_runtime.h>
#include <hip/hip_bf16.h>
#include <math.h>

static inline size_t align_up(size_t x, size_t a) { return (x + a - 1) / a * a; }

typedef short bf16x8 __attribute__((ext_vector_type(8)));
typedef float f32x4 __attribute__((ext_vector_type(4)));
typedef unsigned short u16x8 __attribute__((ext_vector_type(8)));
typedef int i32x4 __attribute__((ext_vector_type(4)));

// ---------------- CSR build via 2-phase LDS-binned bucket sort ----------------
// bucket = dst >> 8 (512 buckets x 256 nodes). No global random atomics:
// bin: LDS counts per chunk + one bump-atomicAdd per bucket per chunk,
//      pairs written to per-bucket staging in ~64B contiguous runs.
// csr: one block per bucket; per-node count+scan in LDS; rowptr/dinv coalesced;
//      esrc scatter confined to the bucket's contiguous ~16KB range (L2-coalesced).

#define NBUCK 512
#define BCAP 8192

__global__ __launch_bounds__(256) void bin_kernel(
    const int* __restrict__ src, const int* __restrict__ dst,
    int* __restrict__ bcnt, long long* __restrict__ staging, int E) {
  __shared__ int lcnt[NBUCK];
  __shared__ int gbase[NBUCK];
  __shared__ int lidx[NBUCK];
  const int tid = threadIdx.x;
  const int base = blockIdx.x * 4096;
  lcnt[tid] = 0; lcnt[tid + 256] = 0;
  lidx[tid] = 0; lidx[tid + 256] = 0;
  __syncthreads();
#pragma unroll
  for (int j = 0; j < 4; ++j) {
    const int idx = base + j * 1024 + tid * 4;
    if (idx + 3 < E) {
      const i32x4 d4 = __builtin_nontemporal_load((const i32x4*)(dst + idx));
#pragma unroll
      for (int c = 0; c < 4; ++c) atomicAdd(&lcnt[d4[c] >> 8], 1);
    } else {
      for (int c = 0; c < 4; ++c)
        if (idx + c < E) atomicAdd(&lcnt[dst[idx + c] >> 8], 1);
    }
  }
  __syncthreads();
  {
    const int c0 = lcnt[tid];
    if (c0 > 0) gbase[tid] = atomicAdd(&bcnt[tid], c0);
    const int c1 = lcnt[tid + 256];
    if (c1 > 0) gbase[tid + 256] = atomicAdd(&bcnt[tid + 256], c1);
  }
  __syncthreads();
#pragma unroll
  for (int j = 0; j < 4; ++j) {
    const int idx = base + j * 1024 + tid * 4;
    if (idx + 3 < E) {
      const i32x4 d4 = __builtin_nontemporal_load((const i32x4*)(dst + idx));
      const i32x4 s4 = __builtin_nontemporal_load((const i32x4*)(src + idx));
#pragma unroll
      for (int c = 0; c < 4; ++c) {
        const int d = d4[c];
        const int bkt = d >> 8;
        const int i = atomicAdd(&lidx[bkt], 1);
        const int pos = gbase[bkt] + i;
        if (pos < BCAP)
          staging[(size_t)bkt * BCAP + pos] =
              (long long)(((unsigned long long)(unsigned)s4[c] << 32) | (unsigned)d);
      }
    } else {
      for (int c = 0; c < 4; ++c) {
        if (idx + c < E) {
          const int d = dst[idx + c];
          const int bkt = d >> 8;
          const int i = atomicAdd(&lidx[bkt], 1);
          const int pos = gbase[bkt] + i;
          if (pos < BCAP)
            staging[(size_t)bkt * BCAP + pos] =
                (long long)(((unsigned long long)(unsigned)src[idx + c] << 32) | (unsigned)d);
        }
      }
    }
  }
}

__global__ __launch_bounds__(512) void bscan_kernel(const int* __restrict__ bcnt,
                                                    int* __restrict__ bbase,
                                                    int* __restrict__ rowptr, int N, int E) {
  __shared__ int sm[NBUCK];
  const int t = threadIdx.x;
  const int v = bcnt[t];
  sm[t] = v;
  __syncthreads();
  for (int o = 1; o < NBUCK; o <<= 1) {
    int x = (t >= o) ? sm[t - o] : 0;
    __syncthreads();
    sm[t] += x;
    __syncthreads();
  }
  bbase[t] = sm[t] - v;
  if (t == 0) rowptr[N] = E;
}

__global__ __launch_bounds__(256) void csr_kernel(
    const long long* __restrict__ staging, const int* __restrict__ bcnt,
    const int* __restrict__ bbase, int* __restrict__ rowptr,
    float* __restrict__ dinv, int* __restrict__ esrc, int N) {
  __shared__ int c1[256];
  __shared__ int off[256];
  __shared__ int sm[256];
  const int b = blockIdx.x;
  const int tid = threadIdx.x;
  const int cnt = min(bcnt[b], BCAP);
  const int base = bbase[b];
  const long long* sp = staging + (size_t)b * BCAP;
  c1[tid] = 0;
  __syncthreads();
  for (int i = tid; i < cnt; i += 256) {
    const int d8 = ((int)sp[i]) & 255;
    atomicAdd(&c1[d8], 1);
  }
  __syncthreads();
  const int deg = c1[tid];
  sm[tid] = deg;
  __syncthreads();
  for (int o = 1; o < 256; o <<= 1) {
    int x = (tid >= o) ? sm[tid - o] : 0;
    __syncthreads();
    sm[tid] += x;
    __syncthreads();
  }
  off[tid] = sm[tid] - deg;
  const int node = b * 256 + tid;
  if (node < N) {
    rowptr[node] = base + off[tid];
    dinv[node] = rsqrtf((float)(deg + 1));
  }
  c1[tid] = 0;
  __syncthreads();
  for (int i = tid; i < cnt; i += 256) {
    const long long pr = sp[i];
    const int d8 = ((int)pr) & 255;
    const int idx = atomicAdd(&c1[d8], 1);
    esrc[base + off[d8] + idx] = (int)(unsigned)((unsigned long long)pr >> 32);
  }
}

// ---------------- split-bf16 helpers ----------------

__device__ __forceinline__ void bf16_split(float x, unsigned short& hi, unsigned short& lo) {
  unsigned u = __float_as_uint(x);
  unsigned r = (u + 0x7fffu + ((u >> 16) & 1u)) & 0xffff0000u;
  hi = (unsigned short)(r >> 16);
  float rem = x - __uint_as_float(r);
  unsigned u2 = __float_as_uint(rem);
  unsigned r2 = u2 + 0x7fffu + ((u2 >> 16) & 1u);
  lo = (unsigned short)(r2 >> 16);
}

__device__ __forceinline__ unsigned short bf16_rtn(float x) {
  unsigned u = __float_as_uint(x);
  return (unsigned short)((u + 0x7fffu + ((u >> 16) & 1u)) >> 16);
}

// Pack both weight matrices into MFMA B-fragment order, split hi/lo bf16.
// Entry (k,n): flat = (((k>>5)*128 + n)*4 + ((k>>3)&3))*8 + (k&7)
__global__ void wsplit_kernel(const float* __restrict__ W1, const float* __restrict__ W2,
                              unsigned short* __restrict__ w1hi, unsigned short* __restrict__ w1lo,
                              unsigned short* __restrict__ w2hi, unsigned short* __restrict__ w2lo) {
  int i = blockIdx.x * blockDim.x + threadIdx.x;
  const int t1 = 160 * 128;
  const int t2 = 128 * 128;
  const float* W;
  unsigned short *whi, *wlo;
  if (i < t1) {
    W = W1; whi = w1hi; wlo = w1lo;
  } else {
    i -= t1;
    if (i >= t2) return;
    W = W2; whi = w2hi; wlo = w2lo;
  }
  int k = i >> 7;
  int n = i & 127;
  unsigned short h, l;
  bf16_split(W[i], h, l);
  size_t idx = ((size_t)(((k >> 5) * 128 + n) * 4 + ((k >> 3) & 3)) << 3) + (k & 7);
  whi[idx] = h;
  wlo[idx] = l;
}

// ---------------- GEMM (layer 1): fp32 A (x|emb concat) -> bf16 out ----------------

__global__ __launch_bounds__(512) void gemm_mfma_kernel(
    const float* __restrict__ A, const float* __restrict__ emb,
    const int* __restrict__ drnl,
    const unsigned short* __restrict__ whi, const unsigned short* __restrict__ wlo,
    unsigned short* __restrict__ outb, int n, int K) {
  __shared__ unsigned short smem[16896];  // B tile hi|lo; epilogue: [128][132] transpose
  const int tid = threadIdx.x;
  const int row0 = blockIdx.x * 128;
  const int w = tid >> 6;
  const int l = tid & 63;
  const int r = l & 15;
  const int q = l >> 4;
  const int grow = row0 + (w << 4) + r;
  const bool rowok = grow < n;
  const int nks = K >> 5;

  int embrow = 0;
  if (K > 128 && rowok) embrow = drnl[grow];

  f32x4 acc[8];
#pragma unroll
  for (int ct = 0; ct < 8; ++ct) {
    acc[ct][0] = 0.f; acc[ct][1] = 0.f; acc[ct][2] = 0.f; acc[ct][3] = 0.f;
  }

  u16x8 bst_h = *(const u16x8*)(whi + (size_t)tid * 8);
  u16x8 bst_l = *(const u16x8*)(wlo + (size_t)tid * 8);

  for (int ks = 0; ks < nks; ++ks) {
    const int k0 = (ks << 5) + (q << 3);
    float4 a0 = make_float4(0.f, 0.f, 0.f, 0.f), a1 = a0;
    if (rowok) {
      if (k0 < 128) {
        const float* ap = A + (size_t)grow * 128 + k0;
        a0 = *(const float4*)ap;
        a1 = *(const float4*)(ap + 4);
      } else {
        const float* ep = emb + (size_t)embrow * 32 + (k0 - 128);
        a0 = *(const float4*)ep;
        a1 = *(const float4*)(ep + 4);
      }
    }
    bf16x8 ah, al;
    {
      unsigned short h, lo_;
      bf16_split(a0.x, h, lo_); ah[0] = (short)h; al[0] = (short)lo_;
      bf16_split(a0.y, h, lo_); ah[1] = (short)h; al[1] = (short)lo_;
      bf16_split(a0.z, h, lo_); ah[2] = (short)h; al[2] = (short)lo_;
      bf16_split(a0.w, h, lo_); ah[3] = (short)h; al[3] = (short)lo_;
      bf16_split(a1.x, h, lo_); ah[4] = (short)h; al[4] = (short)lo_;
      bf16_split(a1.y, h, lo_); ah[5] = (short)h; al[5] = (short)lo_;
      bf16_split(a1.z, h, lo_); ah[6] = (short)h; al[6] = (short)lo_;
      bf16_split(a1.w, h, lo_); ah[7] = (short)h; al[7] = (short)lo_;
    }

    if (ks) __syncthreads();
    *(u16x8*)&smem[tid * 8] = bst_h;
    *(u16x8*)&smem[4096 + tid * 8] = bst_l;
    __syncthreads();

    if (ks + 1 < nks) {
      bst_h = *(const u16x8*)(whi + (size_t)(ks + 1) * 4096 + (size_t)tid * 8);
      bst_l = *(const u16x8*)(wlo + (size_t)(ks + 1) * 4096 + (size_t)tid * 8);
    }

#pragma unroll
    for (int ct = 0; ct < 8; ++ct) {
      const int boff = ((ct << 4) + r) * 32 + (q << 3);
      const bf16x8 bh = *(const bf16x8*)&smem[boff];
      const bf16x8 bl = *(const bf16x8*)&smem[4096 + boff];
      acc[ct] = __builtin_amdgcn_mfma_f32_16x16x32_bf16(ah, bh, acc[ct], 0, 0, 0);
      acc[ct] = __builtin_amdgcn_mfma_f32_16x16x32_bf16(al, bh, acc[ct], 0, 0, 0);
      acc[ct] = __builtin_amdgcn_mfma_f32_16x16x32_bf16(ah, bl, acc[ct], 0, 0, 0);
    }
  }

  __syncthreads();
#pragma unroll
  for (int ct = 0; ct < 8; ++ct) {
    const int col = (ct << 4) + r;
#pragma unroll
    for (int j = 0; j < 4; ++j) {
      const int row = (w << 4) + (q << 2) + j;
      smem[row * 132 + col] = bf16_rtn(acc[ct][j]);
    }
  }
  __syncthreads();
#pragma unroll
  for (int p = 0; p < 4; ++p) {
    const int idx = p * 512 + tid;
    const int row = idx >> 4;
    const int c8 = (idx & 15) * 8;
    const int gr = row0 + row;
    if (gr < n) {
      u16x8 v = *(const u16x8*)&smem[row * 132 + c8];
      *(u16x8*)(outb + (size_t)gr * 128 + c8) = v;
    }
  }
}

// ---------------- GEMM (layer 2): bf16 A -> bf16 out; 2 MFMAs/step ----------------

__global__ __launch_bounds__(512) void gemm_bf16a_kernel(
    const unsigned short* __restrict__ Ab,
    const unsigned short* __restrict__ whi, const unsigned short* __restrict__ wlo,
    unsigned short* __restrict__ outb, int n) {
  __shared__ unsigned short smem[16896];
  const int tid = threadIdx.x;
  const int row0 = blockIdx.x * 128;
  const int w = tid >> 6;
  const int l = tid & 63;
  const int r = l & 15;
  const int q = l >> 4;
  const int grow = row0 + (w << 4) + r;
  const bool rowok = grow < n;
  const int nks = 4;  // K=128

  f32x4 acc[8];
#pragma unroll
  for (int ct = 0; ct < 8; ++ct) {
    acc[ct][0] = 0.f; acc[ct][1] = 0.f; acc[ct][2] = 0.f; acc[ct][3] = 0.f;
  }

  u16x8 bst_h = *(const u16x8*)(whi + (size_t)tid * 8);
  u16x8 bst_l = *(const u16x8*)(wlo + (size_t)tid * 8);

  for (int ks = 0; ks < nks; ++ks) {
    const int k0 = (ks << 5) + (q << 3);
    bf16x8 ah = {0,0,0,0,0,0,0,0};
    if (rowok) ah = *(const bf16x8*)(Ab + (size_t)grow * 128 + k0);

    if (ks) __syncthreads();
    *(u16x8*)&smem[tid * 8] = bst_h;
    *(u16x8*)&smem[4096 + tid * 8] = bst_l;
    __syncthreads();

    if (ks + 1 < nks) {
      bst_h = *(const u16x8*)(whi + (size_t)(ks + 1) * 4096 + (size_t)tid * 8);
      bst_l = *(const u16x8*)(wlo + (size_t)(ks + 1) * 4096 + (size_t)tid * 8);
    }

#pragma unroll
    for (int ct = 0; ct < 8; ++ct) {
      const int boff = ((ct << 4) + r) * 32 + (q << 3);
      const bf16x8 bh = *(const bf16x8*)&smem[boff];
      const bf16x8 bl = *(const bf16x8*)&smem[4096 + boff];
      acc[ct] = __builtin_amdgcn_mfma_f32_16x16x32_bf16(ah, bh, acc[ct], 0, 0, 0);
      acc[ct] = __builtin_amdgcn_mfma_f32_16x16x32_bf16(ah, bl, acc[ct], 0, 0, 0);
    }
  }

  __syncthreads();
#pragma unroll
  for (int ct = 0; ct < 8; ++ct) {
    const int col = (ct << 4) + r;
#pragma unroll
    for (int j = 0; j < 4; ++j) {
      const int row = (w << 4) + (q << 2) + j;
      smem[row * 132 + col] = bf16_rtn(acc[ct][j]);
    }
  }
  __syncthreads();
#pragma unroll
  for (int p = 0; p < 4; ++p) {
    const int idx = p * 512 + tid;
    const int row = idx >> 4;
    const int c8 = (idx & 15) * 8;
    const int gr = row0 + row;
    if (gr < n) {
      u16x8 v = *(const u16x8*)&smem[row * 132 + c8];
      *(u16x8*)(outb + (size_t)gr * 128 + c8) = v;
    }
  }
}

// ---------------- Aggregation: one wave per node, bf16 gather table ----------------

__global__ __launch_bounds__(256) void agg_kernel(
    const unsigned* __restrict__ hwb, const int* __restrict__ rowptr,
    const int* __restrict__ esrc, const float* __restrict__ dinv,
    const float* __restrict__ bias, float* __restrict__ zf,
    unsigned* __restrict__ zb, int n, int obf16) {
  const int widx = (blockIdx.x * blockDim.x + threadIdx.x) >> 6;
  if (widx >= n) return;
  const int wid = __builtin_amdgcn_readfirstlane(widx);
  const int lane = threadIdx.x & 63;
  const int start = rowptr[wid];
  const int end = rowptr[wid + 1];
  const float dn = dinv[wid];
  float ax = 0.f, ay = 0.f;
  int e = start;
  for (; e + 4 <= end; e += 4) {
    const int s0 = esrc[e + 0];
    const int s1 = esrc[e + 1];
    const int s2 = esrc[e + 2];
    const int s3 = esrc[e + 3];
    const float d0 = dinv[s0];
    const float d1 = dinv[s1];
    const float d2 = dinv[s2];
    const float d3 = dinv[s3];
    const unsigned u0 = hwb[(size_t)s0 * 64 + lane];
    const unsigned u1 = hwb[(size_t)s1 * 64 + lane];
    const unsigned u2 = hwb[(size_t)s2 * 64 + lane];
    const unsigned u3 = hwb[(size_t)s3 * 64 + lane];
    const float w0 = d0 * dn;
    const float w1 = d1 * dn;
    const float w2 = d2 * dn;
    const float w3 = d3 * dn;
    ax = fmaf(__uint_as_float(u0 << 16), w0, ax);
    ay = fmaf(__uint_as_float(u0 & 0xffff0000u), w0, ay);
    ax = fmaf(__uint_as_float(u1 << 16), w1, ax);
    ay = fmaf(__uint_as_float(u1 & 0xffff0000u), w1, ay);
    ax = fmaf(__uint_as_float(u2 << 16), w2, ax);
    ay = fmaf(__uint_as_float(u2 & 0xffff0000u), w2, ay);
    ax = fmaf(__uint_as_float(u3 << 16), w3, ax);
    ay = fmaf(__uint_as_float(u3 & 0xffff0000u), w3, ay);
  }
  for (; e < end; ++e) {
    const int s0 = esrc[e];
    const float w0 = dinv[s0] * dn;
    const unsigned u0 = hwb[(size_t)s0 * 64 + lane];
    ax = fmaf(__uint_as_float(u0 << 16), w0, ax);
    ay = fmaf(__uint_as_float(u0 & 0xffff0000u), w0, ay);
  }
  const float sw = dn * dn;
  const unsigned us = hwb[(size_t)wid * 64 + lane];
  ax = fmaf(__uint_as_float(us << 16), sw, ax);
  ay = fmaf(__uint_as_float(us & 0xffff0000u), sw, ay);
  const float2 bb = ((const float2*)bias)[lane];
  float ox = ax + bb.x, oy = ay + bb.y;
  ox = ox > 0.f ? ox : 0.f;
  oy = oy > 0.f ? oy : 0.f;
  if (obf16) {
    const unsigned pw = ((unsigned)bf16_rtn(oy) << 16) | (unsigned)bf16_rtn(ox);
    zb[(size_t)wid * 64 + lane] = pw;
  } else {
    float2 o; o.x = ox; o.y = oy;
    ((float2*)zf)[(size_t)wid * 64 + lane] = o;
  }
}

// ---------------- Head: fused segment-max pool + MLP, one block per graph ----------------

__global__ __launch_bounds__(128) void final_kernel(
    const float* __restrict__ z, const int* __restrict__ tloc,
    const int* __restrict__ ptr,
    const float* __restrict__ Wm1, const float* __restrict__ bm1,
    const float* __restrict__ Wm2, const float* __restrict__ bm2,
    float* __restrict__ out, int npg) {
  __shared__ float feats[640];
  __shared__ float hid[128];
  const int g = blockIdx.x;
  const int t = threadIdx.x;
  const float* zbk = z + (size_t)g * npg * 128;
  float m = -INFINITY;
  for (int r = 0; r < npg; ++r) m = fmaxf(m, zbk[(size_t)r * 128 + t]);
  feats[512 + t] = m;
  const int base = ptr[g];
  const int u = base + tloc[2 * g];
  const int v = base + tloc[2 * g + 1];
  const float hu = z[(size_t)u * 128 + t];
  const float hv = z[(size_t)v * 128 + t];
  feats[t] = hu;
  feats[128 + t] = hv;
  feats[256 + t] = fabsf(hu - hv);
  feats[384 + t] = hu * hv;
  __syncthreads();
  float acc = bm1[t];
#pragma unroll 8
  for (int k = 0; k < 640; ++k) acc = fmaf(feats[k], Wm1[(size_t)k * 128 + t], acc);
  hid[t] = acc > 0.f ? acc : 0.f;
  __syncthreads();
  if (t < 2) {
    float a = bm2[t];
    for (int j = 0; j < 128; ++j) a = fmaf(hid[j], Wm2[j * 2 + t], a);
    out[g * 2 + t] = a;
  }
}

// ---------------- launch ----------------

extern "C" void kernel_launch(void* const* d_in, const int* in_sizes, int n_in,
                              void* d_out, int out_size, void* d_ws, size_t ws_size,
                              hipStream_t stream) {
  const float* x   = (const float*)d_in[0];
  const float* emb = (const float*)d_in[1];
  const float* W1  = (const float*)d_in[2];
  const float* b1  = (const float*)d_in[3];
  const float* W2  = (const float*)d_in[4];
  const float* b2  = (const float*)d_in[5];
  const float* Wm1 = (const float*)d_in[6];
  const float* bm1 = (const float*)d_in[7];
  const float* Wm2 = (const float*)d_in[8];
  const float* bm2 = (const float*)d_in[9];
  const int* eidx  = (const int*)d_in[10];
  const int* drnl  = (const int*)d_in[11];
  const int* tloc  = (const int*)d_in[13];
  const int* ptr   = (const int*)d_in[14];
  float* out = (float*)d_out;

  const int N = in_sizes[11];
  const int E = in_sizes[10] / 2;
  const int G = in_sizes[13] / 2;
  const int NPG = N / G;
  const int* srcp = eidx;
  const int* dstp = eidx + E;

  char* w = (char*)d_ws;
  size_t o = 0;
  auto alloc = [&](size_t bytes) {
    void* p = w + o;
    o = align_up(o + bytes, 256);
    return p;
  };
  int*   rowptr = (int*)alloc((size_t)(N + 1) * 4);
  float* dinv   = (float*)alloc((size_t)N * 4);
  int*   bcnt   = (int*)alloc(NBUCK * 4);
  int*   bbase  = (int*)alloc(NBUCK * 4);
  int*   esrc   = (int*)alloc((size_t)E * 4);
  unsigned short* hwb = (unsigned short*)alloc((size_t)N * 128 * 2);   // bf16 [N][128]
  unsigned short* zb16 = (unsigned short*)alloc((size_t)N * 128 * 2);  // bf16 z (layer1)
  float* z      = (float*)alloc((size_t)N * 128 * 4);                  // fp32 z (layer2)
  long long* staging = (long long*)z;  // 32MB overlay; used only before gemm1
  unsigned short* w1hi = (unsigned short*)alloc((size_t)160 * 128 * 2);
  unsigned short* w1lo = (unsigned short*)alloc((size_t)160 * 128 * 2);
  unsigned short* w2hi = (unsigned short*)alloc((size_t)128 * 128 * 2);
  unsigned short* w2lo = (unsigned short*)alloc((size_t)128 * 128 * 2);

  const int nch = (E + 4095) / 4096;
  const int nbk = (N + 255) / 256;

  hipMemsetAsync(bcnt, 0, NBUCK * 4, stream);
  bin_kernel<<<nch, 256, 0, stream>>>(srcp, dstp, bcnt, staging, E);
  bscan_kernel<<<1, NBUCK, 0, stream>>>(bcnt, bbase, rowptr, N, E);
  csr_kernel<<<nbk, 256, 0, stream>>>(staging, bcnt, bbase, rowptr, dinv, esrc, N);

  wsplit_kernel<<<(160 * 128 + 128 * 128 + 255) / 256, 256, 0, stream>>>(
      W1, W2, w1hi, w1lo, w2hi, w2lo);

  gemm_mfma_kernel<<<(N + 127) / 128, 512, 0, stream>>>(x, emb, drnl, w1hi, w1lo, hwb, N, 160);
  agg_kernel<<<(N * 64 + 255) / 256, 256, 0, stream>>>((const unsigned*)hwb, rowptr, esrc,
                                                       dinv, b1, nullptr, (unsigned*)zb16, N, 1);
  gemm_bf16a_kernel<<<(N + 127) / 128, 512, 0, stream>>>(zb16, w2hi, w2lo, hwb, N);
  agg_kernel<<<(N * 64 + 255) / 256, 256, 0, stream>>>((const unsigned*)hwb, rowptr, esrc,
                                                       dinv, b2, z, nullptr, N, 0);
  final_kernel<<<G, 128, 0, stream>>>(z, tloc, ptr, Wm1, bm1, Wm2, bm2, out, NPG);
}

// Round 12
// 270.153 us; speedup vs baseline: 1.4128x; 1.0266x over previous
//
#include <hip/hip_runtime.h>
#include <hip/hip_bf16.h>
#include <math.h>

static inline size_t align_up(size_t x, size_t a) { return (x + a - 1) / a * a; }

typedef short bf16x8 __attribute__((ext_vector_type(8)));
typedef float f32x4 __attribute__((ext_vector_type(4)));
typedef unsigned short u16x8 __attribute__((ext_vector_type(8)));
typedef int i32x4 __attribute__((ext_vector_type(4)));

// ---------------- CSR build via 2-phase LDS-binned bucket sort ----------------
// bucket = dst >> 8 (512 buckets x 256 nodes). Staging records packed to 4B:
// (src << 8) | (dst & 255)  -- src < 2^17 fits in 24 bits.

#define NBUCK 512
#define BCAP 8192

__global__ __launch_bounds__(256) void bin_kernel(
    const int* __restrict__ src, const int* __restrict__ dst,
    int* __restrict__ bcnt, unsigned* __restrict__ staging, int E) {
  __shared__ int lcnt[NBUCK];
  __shared__ int gbase[NBUCK];
  __shared__ int lidx[NBUCK];
  const int tid = threadIdx.x;
  const int base = blockIdx.x * 4096;
  lcnt[tid] = 0; lcnt[tid + 256] = 0;
  lidx[tid] = 0; lidx[tid + 256] = 0;
  __syncthreads();
#pragma unroll
  for (int j = 0; j < 4; ++j) {
    const int idx = base + j * 1024 + tid * 4;
    if (idx + 3 < E) {
      const i32x4 d4 = __builtin_nontemporal_load((const i32x4*)(dst + idx));
#pragma unroll
      for (int c = 0; c < 4; ++c) atomicAdd(&lcnt[d4[c] >> 8], 1);
    } else {
      for (int c = 0; c < 4; ++c)
        if (idx + c < E) atomicAdd(&lcnt[dst[idx + c] >> 8], 1);
    }
  }
  __syncthreads();
  {
    const int c0 = lcnt[tid];
    if (c0 > 0) gbase[tid] = atomicAdd(&bcnt[tid], c0);
    const int c1 = lcnt[tid + 256];
    if (c1 > 0) gbase[tid + 256] = atomicAdd(&bcnt[tid + 256], c1);
  }
  __syncthreads();
#pragma unroll
  for (int j = 0; j < 4; ++j) {
    const int idx = base + j * 1024 + tid * 4;
    if (idx + 3 < E) {
      const i32x4 d4 = __builtin_nontemporal_load((const i32x4*)(dst + idx));
      const i32x4 s4 = __builtin_nontemporal_load((const i32x4*)(src + idx));
#pragma unroll
      for (int c = 0; c < 4; ++c) {
        const int d = d4[c];
        const int bkt = d >> 8;
        const int i = atomicAdd(&lidx[bkt], 1);
        const int pos = gbase[bkt] + i;
        if (pos < BCAP)
          staging[(size_t)bkt * BCAP + pos] =
              ((unsigned)s4[c] << 8) | ((unsigned)d & 255u);
      }
    } else {
      for (int c = 0; c < 4; ++c) {
        if (idx + c < E) {
          const int d = dst[idx + c];
          const int bkt = d >> 8;
          const int i = atomicAdd(&lidx[bkt], 1);
          const int pos = gbase[bkt] + i;
          if (pos < BCAP)
            staging[(size_t)bkt * BCAP + pos] =
                ((unsigned)src[idx + c] << 8) | ((unsigned)d & 255u);
        }
      }
    }
  }
}

// csr: one block per bucket. Per-block redundant 512-wide bucket scan in LDS
// (replaces separate bscan launch), then per-node count+scan, rowptr/dinv
// coalesced, esrc scatter confined to the bucket's contiguous range.

__global__ __launch_bounds__(256) void csr_kernel(
    const unsigned* __restrict__ staging, const int* __restrict__ bcnt,
    int* __restrict__ rowptr, float* __restrict__ dinv, int* __restrict__ esrc,
    int N, int E) {
  __shared__ int sb[NBUCK];
  __shared__ int c1[256];
  __shared__ int off[256];
  __shared__ int sm[256];
  const int b = blockIdx.x;
  const int tid = threadIdx.x;
  sb[tid] = bcnt[tid];
  sb[tid + 256] = bcnt[tid + 256];
  __syncthreads();
  for (int o = 1; o < NBUCK; o <<= 1) {
    const int x0 = (tid >= o) ? sb[tid - o] : 0;
    const int x1 = (tid + 256 >= o) ? sb[tid + 256 - o] : 0;
    __syncthreads();
    sb[tid] += x0;
    sb[tid + 256] += x1;
    __syncthreads();
  }
  const int cnt = min(bcnt[b], BCAP);
  const int base = sb[b] - bcnt[b];
  if (b == 0 && tid == 0) rowptr[N] = E;
  const unsigned* sp = staging + (size_t)b * BCAP;
  c1[tid] = 0;
  __syncthreads();
  for (int i = tid; i < cnt; i += 256) {
    atomicAdd(&c1[sp[i] & 255u], 1);
  }
  __syncthreads();
  const int deg = c1[tid];
  sm[tid] = deg;
  __syncthreads();
  for (int o = 1; o < 256; o <<= 1) {
    const int x = (tid >= o) ? sm[tid - o] : 0;
    __syncthreads();
    sm[tid] += x;
    __syncthreads();
  }
  off[tid] = sm[tid] - deg;
  const int node = b * 256 + tid;
  if (node < N) {
    rowptr[node] = base + off[tid];
    dinv[node] = rsqrtf((float)(deg + 1));
  }
  c1[tid] = 0;
  __syncthreads();
  for (int i = tid; i < cnt; i += 256) {
    const unsigned pr = sp[i];
    const int d8 = (int)(pr & 255u);
    const int idx = atomicAdd(&c1[d8], 1);
    esrc[base + off[d8] + idx] = (int)(pr >> 8);
  }
}

// ---------------- split-bf16 helpers ----------------

__device__ __forceinline__ void bf16_split(float x, unsigned short& hi, unsigned short& lo) {
  unsigned u = __float_as_uint(x);
  unsigned r = (u + 0x7fffu + ((u >> 16) & 1u)) & 0xffff0000u;
  hi = (unsigned short)(r >> 16);
  float rem = x - __uint_as_float(r);
  unsigned u2 = __float_as_uint(rem);
  unsigned r2 = u2 + 0x7fffu + ((u2 >> 16) & 1u);
  lo = (unsigned short)(r2 >> 16);
}

__device__ __forceinline__ unsigned short bf16_rtn(float x) {
  unsigned u = __float_as_uint(x);
  return (unsigned short)((u + 0x7fffu + ((u >> 16) & 1u)) >> 16);
}

__device__ __forceinline__ float bf16_to_f(unsigned short v) {
  return __uint_as_float((unsigned)v << 16);
}

// Pack both weight matrices into MFMA B-fragment order, split hi/lo bf16.
__global__ void wsplit_kernel(const float* __restrict__ W1, const float* __restrict__ W2,
                              unsigned short* __restrict__ w1hi, unsigned short* __restrict__ w1lo,
                              unsigned short* __restrict__ w2hi, unsigned short* __restrict__ w2lo) {
  int i = blockIdx.x * blockDim.x + threadIdx.x;
  const int t1 = 160 * 128;
  const int t2 = 128 * 128;
  const float* W;
  unsigned short *whi, *wlo;
  if (i < t1) {
    W = W1; whi = w1hi; wlo = w1lo;
  } else {
    i -= t1;
    if (i >= t2) return;
    W = W2; whi = w2hi; wlo = w2lo;
  }
  int k = i >> 7;
  int n = i & 127;
  unsigned short h, l;
  bf16_split(W[i], h, l);
  size_t idx = ((size_t)(((k >> 5) * 128 + n) * 4 + ((k >> 3) & 3)) << 3) + (k & 7);
  whi[idx] = h;
  wlo[idx] = l;
}

// ---------------- GEMM (layer 1): fp32 A (x|emb concat) -> bf16 out ----------------

__global__ __launch_bounds__(512) void gemm_mfma_kernel(
    const float* __restrict__ A, const float* __restrict__ emb,
    const int* __restrict__ drnl,
    const unsigned short* __restrict__ whi, const unsigned short* __restrict__ wlo,
    unsigned short* __restrict__ outb, int n, int K) {
  __shared__ unsigned short smem[16896];  // B tile hi|lo; epilogue: [128][132] transpose
  const int tid = threadIdx.x;
  const int row0 = blockIdx.x * 128;
  const int w = tid >> 6;
  const int l = tid & 63;
  const int r = l & 15;
  const int q = l >> 4;
  const int grow = row0 + (w << 4) + r;
  const bool rowok = grow < n;
  const int nks = K >> 5;

  int embrow = 0;
  if (K > 128 && rowok) embrow = drnl[grow];

  f32x4 acc[8];
#pragma unroll
  for (int ct = 0; ct < 8; ++ct) {
    acc[ct][0] = 0.f; acc[ct][1] = 0.f; acc[ct][2] = 0.f; acc[ct][3] = 0.f;
  }

  u16x8 bst_h = *(const u16x8*)(whi + (size_t)tid * 8);
  u16x8 bst_l = *(const u16x8*)(wlo + (size_t)tid * 8);

  for (int ks = 0; ks < nks; ++ks) {
    const int k0 = (ks << 5) + (q << 3);
    float4 a0 = make_float4(0.f, 0.f, 0.f, 0.f), a1 = a0;
    if (rowok) {
      if (k0 < 128) {
        const float* ap = A + (size_t)grow * 128 + k0;
        a0 = *(const float4*)ap;
        a1 = *(const float4*)(ap + 4);
      } else {
        const float* ep = emb + (size_t)embrow * 32 + (k0 - 128);
        a0 = *(const float4*)ep;
        a1 = *(const float4*)(ep + 4);
      }
    }
    bf16x8 ah, al;
    {
      unsigned short h, lo_;
      bf16_split(a0.x, h, lo_); ah[0] = (short)h; al[0] = (short)lo_;
      bf16_split(a0.y, h, lo_); ah[1] = (short)h; al[1] = (short)lo_;
      bf16_split(a0.z, h, lo_); ah[2] = (short)h; al[2] = (short)lo_;
      bf16_split(a0.w, h, lo_); ah[3] = (short)h; al[3] = (short)lo_;
      bf16_split(a1.x, h, lo_); ah[4] = (short)h; al[4] = (short)lo_;
      bf16_split(a1.y, h, lo_); ah[5] = (short)h; al[5] = (short)lo_;
      bf16_split(a1.z, h, lo_); ah[6] = (short)h; al[6] = (short)lo_;
      bf16_split(a1.w, h, lo_); ah[7] = (short)h; al[7] = (short)lo_;
    }

    if (ks) __syncthreads();
    *(u16x8*)&smem[tid * 8] = bst_h;
    *(u16x8*)&smem[4096 + tid * 8] = bst_l;
    __syncthreads();

    if (ks + 1 < nks) {
      bst_h = *(const u16x8*)(whi + (size_t)(ks + 1) * 4096 + (size_t)tid * 8);
      bst_l = *(const u16x8*)(wlo + (size_t)(ks + 1) * 4096 + (size_t)tid * 8);
    }

#pragma unroll
    for (int ct = 0; ct < 8; ++ct) {
      const int boff = ((ct << 4) + r) * 32 + (q << 3);
      const bf16x8 bh = *(const bf16x8*)&smem[boff];
      const bf16x8 bl = *(const bf16x8*)&smem[4096 + boff];
      acc[ct] = __builtin_amdgcn_mfma_f32_16x16x32_bf16(ah, bh, acc[ct], 0, 0, 0);
      acc[ct] = __builtin_amdgcn_mfma_f32_16x16x32_bf16(al, bh, acc[ct], 0, 0, 0);
      acc[ct] = __builtin_amdgcn_mfma_f32_16x16x32_bf16(ah, bl, acc[ct], 0, 0, 0);
    }
  }

  __syncthreads();
#pragma unroll
  for (int ct = 0; ct < 8; ++ct) {
    const int col = (ct << 4) + r;
#pragma unroll
    for (int j = 0; j < 4; ++j) {
      const int row = (w << 4) + (q << 2) + j;
      smem[row * 132 + col] = bf16_rtn(acc[ct][j]);
    }
  }
  __syncthreads();
#pragma unroll
  for (int p = 0; p < 4; ++p) {
    const int idx = p * 512 + tid;
    const int row = idx >> 4;
    const int c8 = (idx & 15) * 8;
    const int gr = row0 + row;
    if (gr < n) {
      u16x8 v = *(const u16x8*)&smem[row * 132 + c8];
      *(u16x8*)(outb + (size_t)gr * 128 + c8) = v;
    }
  }
}

// ---------------- GEMM (layer 2): bf16 A -> bf16 out; 2 MFMAs/step ----------------

__global__ __launch_bounds__(512) void gemm_bf16a_kernel(
    const unsigned short* __restrict__ Ab,
    const unsigned short* __restrict__ whi, const unsigned short* __restrict__ wlo,
    unsigned short* __restrict__ outb, int n) {
  __shared__ unsigned short smem[16896];
  const int tid = threadIdx.x;
  const int row0 = blockIdx.x * 128;
  const int w = tid >> 6;
  const int l = tid & 63;
  const int r = l & 15;
  const int q = l >> 4;
  const int grow = row0 + (w << 4) + r;
  const bool rowok = grow < n;
  const int nks = 4;  // K=128

  f32x4 acc[8];
#pragma unroll
  for (int ct = 0; ct < 8; ++ct) {
    acc[ct][0] = 0.f; acc[ct][1] = 0.f; acc[ct][2] = 0.f; acc[ct][3] = 0.f;
  }

  u16x8 bst_h = *(const u16x8*)(whi + (size_t)tid * 8);
  u16x8 bst_l = *(const u16x8*)(wlo + (size_t)tid * 8);

  for (int ks = 0; ks < nks; ++ks) {
    const int k0 = (ks << 5) + (q << 3);
    bf16x8 ah = {0,0,0,0,0,0,0,0};
    if (rowok) ah = *(const bf16x8*)(Ab + (size_t)grow * 128 + k0);

    if (ks) __syncthreads();
    *(u16x8*)&smem[tid * 8] = bst_h;
    *(u16x8*)&smem[4096 + tid * 8] = bst_l;
    __syncthreads();

    if (ks + 1 < nks) {
      bst_h = *(const u16x8*)(whi + (size_t)(ks + 1) * 4096 + (size_t)tid * 8);
      bst_l = *(const u16x8*)(wlo + (size_t)(ks + 1) * 4096 + (size_t)tid * 8);
    }

#pragma unroll
    for (int ct = 0; ct < 8; ++ct) {
      const int boff = ((ct << 4) + r) * 32 + (q << 3);
      const bf16x8 bh = *(const bf16x8*)&smem[boff];
      const bf16x8 bl = *(const bf16x8*)&smem[4096 + boff];
      acc[ct] = __builtin_amdgcn_mfma_f32_16x16x32_bf16(ah, bh, acc[ct], 0, 0, 0);
      acc[ct] = __builtin_amdgcn_mfma_f32_16x16x32_bf16(ah, bl, acc[ct], 0, 0, 0);
    }
  }

  __syncthreads();
#pragma unroll
  for (int ct = 0; ct < 8; ++ct) {
    const int col = (ct << 4) + r;
#pragma unroll
    for (int j = 0; j < 4; ++j) {
      const int row = (w << 4) + (q << 2) + j;
      smem[row * 132 + col] = bf16_rtn(acc[ct][j]);
    }
  }
  __syncthreads();
#pragma unroll
  for (int p = 0; p < 4; ++p) {
    const int idx = p * 512 + tid;
    const int row = idx >> 4;
    const int c8 = (idx & 15) * 8;
    const int gr = row0 + row;
    if (gr < n) {
      u16x8 v = *(const u16x8*)&smem[row * 132 + c8];
      *(u16x8*)(outb + (size_t)gr * 128 + c8) = v;
    }
  }
}

// ---------------- Aggregation: one wave per node, bf16 gather table, unroll 8 ----------------
// esrc/dinv loads are wave-uniform (scalar); 8 independent 256B gathers in flight.
// Output always packed bf16 (z feeds gemm2 / head).

__global__ __launch_bounds__(256) void agg_kernel(
    const unsigned* __restrict__ hwb, const int* __restrict__ rowptr,
    const int* __restrict__ esrc, const float* __restrict__ dinv,
    const float* __restrict__ bias, unsigned* __restrict__ zb, int n) {
  const int widx = (blockIdx.x * blockDim.x + threadIdx.x) >> 6;
  if (widx >= n) return;
  const int wid = __builtin_amdgcn_readfirstlane(widx);
  const int lane = threadIdx.x & 63;
  const int start = rowptr[wid];
  const int end = rowptr[wid + 1];
  const float dn = dinv[wid];
  float ax = 0.f, ay = 0.f;
  int e = start;
  for (; e + 8 <= end; e += 8) {
    int s[8];
#pragma unroll
    for (int k = 0; k < 8; ++k) s[k] = esrc[e + k];
    unsigned u[8];
#pragma unroll
    for (int k = 0; k < 8; ++k) u[k] = hwb[(size_t)s[k] * 64 + lane];
    float dv[8];
#pragma unroll
    for (int k = 0; k < 8; ++k) dv[k] = dinv[s[k]];
#pragma unroll
    for (int k = 0; k < 8; ++k) {
      const float wk = dv[k] * dn;
      ax = fmaf(__uint_as_float(u[k] << 16), wk, ax);
      ay = fmaf(__uint_as_float(u[k] & 0xffff0000u), wk, ay);
    }
  }
  for (; e < end; ++e) {
    const int s0 = esrc[e];
    const float w0 = dinv[s0] * dn;
    const unsigned u0 = hwb[(size_t)s0 * 64 + lane];
    ax = fmaf(__uint_as_float(u0 << 16), w0, ax);
    ay = fmaf(__uint_as_float(u0 & 0xffff0000u), w0, ay);
  }
  const float sw = dn * dn;
  const unsigned us = hwb[(size_t)wid * 64 + lane];
  ax = fmaf(__uint_as_float(us << 16), sw, ax);
  ay = fmaf(__uint_as_float(us & 0xffff0000u), sw, ay);
  const float2 bb = ((const float2*)bias)[lane];
  float ox = ax + bb.x, oy = ay + bb.y;
  ox = ox > 0.f ? ox : 0.f;
  oy = oy > 0.f ? oy : 0.f;
  const unsigned pw = ((unsigned)bf16_rtn(oy) << 16) | (unsigned)bf16_rtn(ox);
  zb[(size_t)wid * 64 + lane] = pw;
}

// ---------------- Head: fused segment-max pool + MLP (bf16 z input) ----------------

__global__ __launch_bounds__(128) void final_kernel(
    const unsigned short* __restrict__ zb, const int* __restrict__ tloc,
    const int* __restrict__ ptr,
    const float* __restrict__ Wm1, const float* __restrict__ bm1,
    const float* __restrict__ Wm2, const float* __restrict__ bm2,
    float* __restrict__ out, int npg) {
  __shared__ float feats[640];
  __shared__ float hid[128];
  const int g = blockIdx.x;
  const int t = threadIdx.x;
  const unsigned short* zbk = zb + (size_t)g * npg * 128;
  float m = -INFINITY;
  for (int r = 0; r < npg; ++r) m = fmaxf(m, bf16_to_f(zbk[(size_t)r * 128 + t]));
  feats[512 + t] = m;
  const int base = ptr[g];
  const int u = base + tloc[2 * g];
  const int v = base + tloc[2 * g + 1];
  const float hu = bf16_to_f(zb[(size_t)u * 128 + t]);
  const float hv = bf16_to_f(zb[(size_t)v * 128 + t]);
  feats[t] = hu;
  feats[128 + t] = hv;
  feats[256 + t] = fabsf(hu - hv);
  feats[384 + t] = hu * hv;
  __syncthreads();
  float acc = bm1[t];
#pragma unroll 8
  for (int k = 0; k < 640; ++k) acc = fmaf(feats[k], Wm1[(size_t)k * 128 + t], acc);
  hid[t] = acc > 0.f ? acc : 0.f;
  __syncthreads();
  if (t < 2) {
    float a = bm2[t];
    for (int j = 0; j < 128; ++j) a = fmaf(hid[j], Wm2[j * 2 + t], a);
    out[g * 2 + t] = a;
  }
}

// ---------------- launch ----------------

extern "C" void kernel_launch(void* const* d_in, const int* in_sizes, int n_in,
                              void* d_out, int out_size, void* d_ws, size_t ws_size,
                              hipStream_t stream) {
  const float* x   = (const float*)d_in[0];
  const float* emb = (const float*)d_in[1];
  const float* W1  = (const float*)d_in[2];
  const float* b1  = (const float*)d_in[3];
  const float* W2  = (const float*)d_in[4];
  const float* b2  = (const float*)d_in[5];
  const float* Wm1 = (const float*)d_in[6];
  const float* bm1 = (const float*)d_in[7];
  const float* Wm2 = (const float*)d_in[8];
  const float* bm2 = (const float*)d_in[9];
  const int* eidx  = (const int*)d_in[10];
  const int* drnl  = (const int*)d_in[11];
  const int* tloc  = (const int*)d_in[13];
  const int* ptr   = (const int*)d_in[14];
  float* out = (float*)d_out;

  const int N = in_sizes[11];
  const int E = in_sizes[10] / 2;
  const int G = in_sizes[13] / 2;
  const int NPG = N / G;
  const int* srcp = eidx;
  const int* dstp = eidx + E;

  char* w = (char*)d_ws;
  size_t o = 0;
  auto alloc = [&](size_t bytes) {
    void* p = w + o;
    o = align_up(o + bytes, 256);
    return p;
  };
  int*   rowptr = (int*)alloc((size_t)(N + 1) * 4);
  float* dinv   = (float*)alloc((size_t)N * 4);
  int*   bcnt   = (int*)alloc(NBUCK * 4);
  int*   esrc   = (int*)alloc((size_t)E * 4);
  unsigned short* hwb  = (unsigned short*)alloc((size_t)N * 128 * 2);  // bf16 [N][128]
  unsigned short* zb1  = (unsigned short*)alloc((size_t)N * 128 * 2);  // bf16 z layer1
  unsigned short* zb2  = (unsigned short*)alloc((size_t)N * 128 * 2);  // bf16 z layer2
  unsigned* staging = (unsigned*)zb2;  // 16.8MB overlay; used only before gemm1
  unsigned short* w1hi = (unsigned short*)alloc((size_t)160 * 128 * 2);
  unsigned short* w1lo = (unsigned short*)alloc((size_t)160 * 128 * 2);
  unsigned short* w2hi = (unsigned short*)alloc((size_t)128 * 128 * 2);
  unsigned short* w2lo = (unsigned short*)alloc((size_t)128 * 128 * 2);

  const int nch = (E + 4095) / 4096;
  const int nbk = (N + 255) / 256;

  hipMemsetAsync(bcnt, 0, NBUCK * 4, stream);
  bin_kernel<<<nch, 256, 0, stream>>>(srcp, dstp, bcnt, staging, E);
  csr_kernel<<<nbk, 256, 0, stream>>>(staging, bcnt, rowptr, dinv, esrc, N, E);

  wsplit_kernel<<<(160 * 128 + 128 * 128 + 255) / 256, 256, 0, stream>>>(
      W1, W2, w1hi, w1lo, w2hi, w2lo);

  gemm_mfma_kernel<<<(N + 127) / 128, 512, 0, stream>>>(x, emb, drnl, w1hi, w1lo, hwb, N, 160);
  agg_kernel<<<(N * 64 + 255) / 256, 256, 0, stream>>>((const unsigned*)hwb, rowptr, esrc,
                                                       dinv, b1, (unsigned*)zb1, N);
  gemm_bf16a_kernel<<<(N + 127) / 128, 512, 0, stream>>>(zb1, w2hi, w2lo, hwb, N);
  agg_kernel<<<(N * 64 + 255) / 256, 256, 0, stream>>>((const unsigned*)hwb, rowptr, esrc,
                                                       dinv, b2, (unsigned*)zb2, N);
  final_kernel<<<G, 128, 0, stream>>>(zb2, tloc, ptr, Wm1, bm1, Wm2, bm2, out, NPG);
}

// Round 13
// 258.513 us; speedup vs baseline: 1.4764x; 1.0450x over previous
//
#include <hip/hip_runtime.h>
#include <hip/hip_bf16.h>
#include <math.h>

static inline size_t align_up(size_t x, size_t a) { return (x + a - 1) / a * a; }

typedef short bf16x8 __attribute__((ext_vector_type(8)));
typedef float f32x4 __attribute__((ext_vector_type(4)));
typedef unsigned short u16x8 __attribute__((ext_vector_type(8)));
typedef int i32x4 __attribute__((ext_vector_type(4)));

#define NBUCK 512
#define BCAP 8192

// ---------------- split-bf16 helpers ----------------

__device__ __forceinline__ void bf16_split(float x, unsigned short& hi, unsigned short& lo) {
  unsigned u = __float_as_uint(x);
  unsigned r = (u + 0x7fffu + ((u >> 16) & 1u)) & 0xffff0000u;
  hi = (unsigned short)(r >> 16);
  float rem = x - __uint_as_float(r);
  unsigned u2 = __float_as_uint(rem);
  unsigned r2 = u2 + 0x7fffu + ((u2 >> 16) & 1u);
  lo = (unsigned short)(r2 >> 16);
}

__device__ __forceinline__ unsigned short bf16_rtn(float x) {
  unsigned u = __float_as_uint(x);
  return (unsigned short)((u + 0x7fffu + ((u >> 16) & 1u)) >> 16);
}

__device__ __forceinline__ float bf16_to_f(unsigned short v) {
  return __uint_as_float((unsigned)v << 16);
}

// ---------------- bin (+fused wsplit tail blocks) ----------------
// Blocks [0,nch): LDS-binned bucket scatter. Pass 1 reads src/dst once (nt),
// stashes packed rec + bucket in LDS; pass 2 scatters from LDS (no re-read).
// Blocks [nch, nch+144): weight split/pack (independent work, overlapped).

__global__ __launch_bounds__(256) void bin_kernel(
    const int* __restrict__ src, const int* __restrict__ dst,
    int* __restrict__ bcnt, unsigned* __restrict__ staging, int E, int nch,
    const float* __restrict__ W1, const float* __restrict__ W2,
    unsigned short* __restrict__ w1hi, unsigned short* __restrict__ w1lo,
    unsigned short* __restrict__ w2hi, unsigned short* __restrict__ w2lo) {
  const int tid = threadIdx.x;
  if ((int)blockIdx.x >= nch) {  // ---- fused wsplit ----
    int i = ((int)blockIdx.x - nch) * 256 + tid;
    const int t1 = 160 * 128;
    const int t2 = 128 * 128;
    const float* W;
    unsigned short *whi, *wlo;
    if (i < t1) {
      W = W1; whi = w1hi; wlo = w1lo;
    } else {
      i -= t1;
      if (i >= t2) return;
      W = W2; whi = w2hi; wlo = w2lo;
    }
    int k = i >> 7;
    int n = i & 127;
    unsigned short h, l;
    bf16_split(W[i], h, l);
    size_t idx = ((size_t)(((k >> 5) * 128 + n) * 4 + ((k >> 3) & 3)) << 3) + (k & 7);
    whi[idx] = h;
    wlo[idx] = l;
    return;
  }
  __shared__ int lcnt[NBUCK];
  __shared__ int gbase[NBUCK];
  __shared__ int lidx[NBUCK];
  __shared__ unsigned srec[4096];
  __shared__ unsigned short sbkt[4096];
  const int base = blockIdx.x * 4096;
  lcnt[tid] = 0; lcnt[tid + 256] = 0;
  lidx[tid] = 0; lidx[tid + 256] = 0;
  __syncthreads();
#pragma unroll
  for (int j = 0; j < 4; ++j) {
    const int slot = j * 1024 + tid * 4;
    const int idx = base + slot;
    if (idx + 3 < E) {
      const i32x4 d4 = __builtin_nontemporal_load((const i32x4*)(dst + idx));
      const i32x4 s4 = __builtin_nontemporal_load((const i32x4*)(src + idx));
#pragma unroll
      for (int c = 0; c < 4; ++c) {
        const int d = d4[c];
        const int bkt = d >> 8;
        atomicAdd(&lcnt[bkt], 1);
        srec[slot + c] = ((unsigned)s4[c] << 8) | ((unsigned)d & 255u);
        sbkt[slot + c] = (unsigned short)bkt;
      }
    } else {
      for (int c = 0; c < 4; ++c) {
        if (idx + c < E) {
          const int d = dst[idx + c];
          const int bkt = d >> 8;
          atomicAdd(&lcnt[bkt], 1);
          srec[slot + c] = ((unsigned)src[idx + c] << 8) | ((unsigned)d & 255u);
          sbkt[slot + c] = (unsigned short)bkt;
        } else {
          sbkt[slot + c] = 0xFFFFu;
        }
      }
    }
  }
  __syncthreads();
  {
    const int c0 = lcnt[tid];
    if (c0 > 0) gbase[tid] = atomicAdd(&bcnt[tid], c0);
    const int c1 = lcnt[tid + 256];
    if (c1 > 0) gbase[tid + 256] = atomicAdd(&bcnt[tid + 256], c1);
  }
  __syncthreads();
#pragma unroll
  for (int j = 0; j < 4; ++j) {
    const int slot = j * 1024 + tid * 4;
#pragma unroll
    for (int c = 0; c < 4; ++c) {
      const int bkt = sbkt[slot + c];
      if (bkt != 0xFFFF) {
        const int i = atomicAdd(&lidx[bkt], 1);
        const int pos = gbase[bkt] + i;
        if (pos < BCAP) staging[(size_t)bkt * BCAP + pos] = srec[slot + c];
      }
    }
  }
}

// ---------------- csr: one block per bucket ----------------

__global__ __launch_bounds__(256) void csr_kernel(
    const unsigned* __restrict__ staging, const int* __restrict__ bcnt,
    int* __restrict__ rowptr, float* __restrict__ dinv, int* __restrict__ esrc,
    int N, int E) {
  __shared__ int sb[NBUCK];
  __shared__ int c1[256];
  __shared__ int off[256];
  __shared__ int sm[256];
  const int b = blockIdx.x;
  const int tid = threadIdx.x;
  sb[tid] = bcnt[tid];
  sb[tid + 256] = bcnt[tid + 256];
  __syncthreads();
  for (int o = 1; o < NBUCK; o <<= 1) {
    const int x0 = (tid >= o) ? sb[tid - o] : 0;
    const int x1 = (tid + 256 >= o) ? sb[tid + 256 - o] : 0;
    __syncthreads();
    sb[tid] += x0;
    sb[tid + 256] += x1;
    __syncthreads();
  }
  const int cnt = min(bcnt[b], BCAP);
  const int base = sb[b] - bcnt[b];
  if (b == 0 && tid == 0) rowptr[N] = E;
  const unsigned* sp = staging + (size_t)b * BCAP;
  c1[tid] = 0;
  __syncthreads();
  for (int i = tid; i < cnt; i += 256) {
    atomicAdd(&c1[sp[i] & 255u], 1);
  }
  __syncthreads();
  const int deg = c1[tid];
  sm[tid] = deg;
  __syncthreads();
  for (int o = 1; o < 256; o <<= 1) {
    const int x = (tid >= o) ? sm[tid - o] : 0;
    __syncthreads();
    sm[tid] += x;
    __syncthreads();
  }
  off[tid] = sm[tid] - deg;
  const int node = b * 256 + tid;
  if (node < N) {
    rowptr[node] = base + off[tid];
    dinv[node] = rsqrtf((float)(deg + 1));
  }
  c1[tid] = 0;
  __syncthreads();
  for (int i = tid; i < cnt; i += 256) {
    const unsigned pr = sp[i];
    const int d8 = (int)(pr & 255u);
    const int idx = atomicAdd(&c1[d8], 1);
    esrc[base + off[d8] + idx] = (int)(pr >> 8);
  }
}

// ---------------- GEMM (layer 1): fp32 A (x|emb) -> bf16 out, dbuf B, 1 barrier/ks ----------------

__global__ __launch_bounds__(512) void gemm_mfma_kernel(
    const float* __restrict__ A, const float* __restrict__ emb,
    const int* __restrict__ drnl,
    const unsigned short* __restrict__ whi, const unsigned short* __restrict__ wlo,
    unsigned short* __restrict__ outb, int n) {
  __shared__ unsigned short smem[16896];  // 2 B-tiles (2x8192); epilogue reuses [128][132]
  const int tid = threadIdx.x;
  const int row0 = blockIdx.x * 128;
  const int w = tid >> 6;
  const int l = tid & 63;
  const int r = l & 15;
  const int q = l >> 4;
  const int grow = row0 + (w << 4) + r;
  const bool rowok = grow < n;
  const int NKS = 5;  // K=160

  int embrow = 0;
  if (rowok) embrow = drnl[grow];

  f32x4 acc[8];
#pragma unroll
  for (int ct = 0; ct < 8; ++ct) {
    acc[ct][0] = 0.f; acc[ct][1] = 0.f; acc[ct][2] = 0.f; acc[ct][3] = 0.f;
  }

  // prologue: tile 0 -> buf0, prefetch tile 1 regs
  u16x8 bst_h = *(const u16x8*)(whi + (size_t)tid * 8);
  u16x8 bst_l = *(const u16x8*)(wlo + (size_t)tid * 8);
  *(u16x8*)&smem[tid * 8] = bst_h;
  *(u16x8*)&smem[4096 + tid * 8] = bst_l;
  bst_h = *(const u16x8*)(whi + 4096 + (size_t)tid * 8);
  bst_l = *(const u16x8*)(wlo + 4096 + (size_t)tid * 8);
  __syncthreads();

#pragma unroll
  for (int ks = 0; ks < NKS; ++ks) {
    // A fragment for this K-step -> regs, split hi/lo
    const int k0 = (ks << 5) + (q << 3);
    float4 a0 = make_float4(0.f, 0.f, 0.f, 0.f), a1 = a0;
    if (rowok) {
      if (k0 < 128) {
        const float* ap = A + (size_t)grow * 128 + k0;
        a0 = *(const float4*)ap;
        a1 = *(const float4*)(ap + 4);
      } else {
        const float* ep = emb + (size_t)embrow * 32 + (k0 - 128);
        a0 = *(const float4*)ep;
        a1 = *(const float4*)(ep + 4);
      }
    }
    bf16x8 ah, al;
    {
      unsigned short h, lo_;
      bf16_split(a0.x, h, lo_); ah[0] = (short)h; al[0] = (short)lo_;
      bf16_split(a0.y, h, lo_); ah[1] = (short)h; al[1] = (short)lo_;
      bf16_split(a0.z, h, lo_); ah[2] = (short)h; al[2] = (short)lo_;
      bf16_split(a0.w, h, lo_); ah[3] = (short)h; al[3] = (short)lo_;
      bf16_split(a1.x, h, lo_); ah[4] = (short)h; al[4] = (short)lo_;
      bf16_split(a1.y, h, lo_); ah[5] = (short)h; al[5] = (short)lo_;
      bf16_split(a1.z, h, lo_); ah[6] = (short)h; al[6] = (short)lo_;
      bf16_split(a1.w, h, lo_); ah[7] = (short)h; al[7] = (short)lo_;
    }

    // publish next tile (regs loaded last iter) to the other buffer; prefetch ks+2
    if (ks + 1 < NKS) {
      const int nxt = ((ks + 1) & 1) * 8192;
      *(u16x8*)&smem[nxt + tid * 8] = bst_h;
      *(u16x8*)&smem[nxt + 4096 + tid * 8] = bst_l;
      if (ks + 2 < NKS) {
        bst_h = *(const u16x8*)(whi + (size_t)(ks + 2) * 4096 + (size_t)tid * 8);
        bst_l = *(const u16x8*)(wlo + (size_t)(ks + 2) * 4096 + (size_t)tid * 8);
      }
    }

    const int cur = (ks & 1) * 8192;
#pragma unroll
    for (int ct = 0; ct < 8; ++ct) {
      const int boff = cur + ((ct << 4) + r) * 32 + (q << 3);
      const bf16x8 bh = *(const bf16x8*)&smem[boff];
      const bf16x8 bl = *(const bf16x8*)&smem[boff + 4096];
      acc[ct] = __builtin_amdgcn_mfma_f32_16x16x32_bf16(ah, bh, acc[ct], 0, 0, 0);
      acc[ct] = __builtin_amdgcn_mfma_f32_16x16x32_bf16(al, bh, acc[ct], 0, 0, 0);
      acc[ct] = __builtin_amdgcn_mfma_f32_16x16x32_bf16(ah, bl, acc[ct], 0, 0, 0);
    }
    __syncthreads();
  }

  // epilogue: bf16 round -> LDS transpose ([128][132]) -> coalesced 16B stores
#pragma unroll
  for (int ct = 0; ct < 8; ++ct) {
    const int col = (ct << 4) + r;
#pragma unroll
    for (int j = 0; j < 4; ++j) {
      const int row = (w << 4) + (q << 2) + j;
      smem[row * 132 + col] = bf16_rtn(acc[ct][j]);
    }
  }
  __syncthreads();
#pragma unroll
  for (int p = 0; p < 4; ++p) {
    const int idx = p * 512 + tid;
    const int row = idx >> 4;
    const int c8 = (idx & 15) * 8;
    const int gr = row0 + row;
    if (gr < n) {
      u16x8 v = *(const u16x8*)&smem[row * 132 + c8];
      *(u16x8*)(outb + (size_t)gr * 128 + c8) = v;
    }
  }
}

// ---------------- GEMM (layer 2): bf16 A -> bf16 out; 2 MFMAs/step, dbuf B ----------------

__global__ __launch_bounds__(512) void gemm_bf16a_kernel(
    const unsigned short* __restrict__ Ab,
    const unsigned short* __restrict__ whi, const unsigned short* __restrict__ wlo,
    unsigned short* __restrict__ outb, int n) {
  __shared__ unsigned short smem[16896];
  const int tid = threadIdx.x;
  const int row0 = blockIdx.x * 128;
  const int w = tid >> 6;
  const int l = tid & 63;
  const int r = l & 15;
  const int q = l >> 4;
  const int grow = row0 + (w << 4) + r;
  const bool rowok = grow < n;
  const int NKS = 4;  // K=128

  f32x4 acc[8];
#pragma unroll
  for (int ct = 0; ct < 8; ++ct) {
    acc[ct][0] = 0.f; acc[ct][1] = 0.f; acc[ct][2] = 0.f; acc[ct][3] = 0.f;
  }

  u16x8 bst_h = *(const u16x8*)(whi + (size_t)tid * 8);
  u16x8 bst_l = *(const u16x8*)(wlo + (size_t)tid * 8);
  *(u16x8*)&smem[tid * 8] = bst_h;
  *(u16x8*)&smem[4096 + tid * 8] = bst_l;
  bst_h = *(const u16x8*)(whi + 4096 + (size_t)tid * 8);
  bst_l = *(const u16x8*)(wlo + 4096 + (size_t)tid * 8);
  __syncthreads();

#pragma unroll
  for (int ks = 0; ks < NKS; ++ks) {
    const int k0 = (ks << 5) + (q << 3);
    bf16x8 ah = {0,0,0,0,0,0,0,0};
    if (rowok) ah = *(const bf16x8*)(Ab + (size_t)grow * 128 + k0);

    if (ks + 1 < NKS) {
      const int nxt = ((ks + 1) & 1) * 8192;
      *(u16x8*)&smem[nxt + tid * 8] = bst_h;
      *(u16x8*)&smem[nxt + 4096 + tid * 8] = bst_l;
      if (ks + 2 < NKS) {
        bst_h = *(const u16x8*)(whi + (size_t)(ks + 2) * 4096 + (size_t)tid * 8);
        bst_l = *(const u16x8*)(wlo + (size_t)(ks + 2) * 4096 + (size_t)tid * 8);
      }
    }

    const int cur = (ks & 1) * 8192;
#pragma unroll
    for (int ct = 0; ct < 8; ++ct) {
      const int boff = cur + ((ct << 4) + r) * 32 + (q << 3);
      const bf16x8 bh = *(const bf16x8*)&smem[boff];
      const bf16x8 bl = *(const bf16x8*)&smem[boff + 4096];
      acc[ct] = __builtin_amdgcn_mfma_f32_16x16x32_bf16(ah, bh, acc[ct], 0, 0, 0);
      acc[ct] = __builtin_amdgcn_mfma_f32_16x16x32_bf16(ah, bl, acc[ct], 0, 0, 0);
    }
    __syncthreads();
  }

#pragma unroll
  for (int ct = 0; ct < 8; ++ct) {
    const int col = (ct << 4) + r;
#pragma unroll
    for (int j = 0; j < 4; ++j) {
      const int row = (w << 4) + (q << 2) + j;
      smem[row * 132 + col] = bf16_rtn(acc[ct][j]);
    }
  }
  __syncthreads();
#pragma unroll
  for (int p = 0; p < 4; ++p) {
    const int idx = p * 512 + tid;
    const int row = idx >> 4;
    const int c8 = (idx & 15) * 8;
    const int gr = row0 + row;
    if (gr < n) {
      u16x8 v = *(const u16x8*)&smem[row * 132 + c8];
      *(u16x8*)(outb + (size_t)gr * 128 + c8) = v;
    }
  }
}

// ---------------- Aggregation: one wave per node, bf16 gather table, unroll 8 ----------------

__global__ __launch_bounds__(256) void agg_kernel(
    const unsigned* __restrict__ hwb, const int* __restrict__ rowptr,
    const int* __restrict__ esrc, const float* __restrict__ dinv,
    const float* __restrict__ bias, unsigned* __restrict__ zb, int n) {
  const int widx = (blockIdx.x * blockDim.x + threadIdx.x) >> 6;
  if (widx >= n) return;
  const int wid = __builtin_amdgcn_readfirstlane(widx);
  const int lane = threadIdx.x & 63;
  const int start = rowptr[wid];
  const int end = rowptr[wid + 1];
  const float dn = dinv[wid];
  float ax = 0.f, ay = 0.f;
  int e = start;
  for (; e + 8 <= end; e += 8) {
    int s[8];
#pragma unroll
    for (int k = 0; k < 8; ++k) s[k] = esrc[e + k];
    unsigned u[8];
#pragma unroll
    for (int k = 0; k < 8; ++k) u[k] = hwb[(size_t)s[k] * 64 + lane];
    float dv[8];
#pragma unroll
    for (int k = 0; k < 8; ++k) dv[k] = dinv[s[k]];
#pragma unroll
    for (int k = 0; k < 8; ++k) {
      const float wk = dv[k] * dn;
      ax = fmaf(__uint_as_float(u[k] << 16), wk, ax);
      ay = fmaf(__uint_as_float(u[k] & 0xffff0000u), wk, ay);
    }
  }
  for (; e < end; ++e) {
    const int s0 = esrc[e];
    const float w0 = dinv[s0] * dn;
    const unsigned u0 = hwb[(size_t)s0 * 64 + lane];
    ax = fmaf(__uint_as_float(u0 << 16), w0, ax);
    ay = fmaf(__uint_as_float(u0 & 0xffff0000u), w0, ay);
  }
  const float sw = dn * dn;
  const unsigned us = hwb[(size_t)wid * 64 + lane];
  ax = fmaf(__uint_as_float(us << 16), sw, ax);
  ay = fmaf(__uint_as_float(us & 0xffff0000u), sw, ay);
  const float2 bb = ((const float2*)bias)[lane];
  float ox = ax + bb.x, oy = ay + bb.y;
  ox = ox > 0.f ? ox : 0.f;
  oy = oy > 0.f ? oy : 0.f;
  const unsigned pw = ((unsigned)bf16_rtn(oy) << 16) | (unsigned)bf16_rtn(ox);
  zb[(size_t)wid * 64 + lane] = pw;
}

// ---------------- Head: fused segment-max pool + MLP (bf16 z input) ----------------

__global__ __launch_bounds__(128) void final_kernel(
    const unsigned short* __restrict__ zb, const int* __restrict__ tloc,
    const int* __restrict__ ptr,
    const float* __restrict__ Wm1, const float* __restrict__ bm1,
    const float* __restrict__ Wm2, const float* __restrict__ bm2,
    float* __restrict__ out, int npg) {
  __shared__ float feats[640];
  __shared__ float hid[128];
  __shared__ float pm[2][128];
  const int g = blockIdx.x;
  const int t = threadIdx.x;
  // pool: thread t handles col-pair p=(t&63) for row-parity h=(t>>6)
  {
    const unsigned* zrow = (const unsigned*)(zb + (size_t)g * npg * 128);
    const int p = t & 63;
    const int h = t >> 6;
    float m0 = -INFINITY, m1 = -INFINITY;
    for (int r = h; r < npg; r += 2) {
      const unsigned u = zrow[(size_t)r * 64 + p];
      m0 = fmaxf(m0, __uint_as_float(u << 16));
      m1 = fmaxf(m1, __uint_as_float(u & 0xffff0000u));
    }
    pm[h][2 * p] = m0;
    pm[h][2 * p + 1] = m1;
  }
  const int base = ptr[g];
  const int u = base + tloc[2 * g];
  const int v = base + tloc[2 * g + 1];
  const float hu = bf16_to_f(zb[(size_t)u * 128 + t]);
  const float hv = bf16_to_f(zb[(size_t)v * 128 + t]);
  feats[t] = hu;
  feats[128 + t] = hv;
  feats[256 + t] = fabsf(hu - hv);
  feats[384 + t] = hu * hv;
  __syncthreads();
  feats[512 + t] = fmaxf(pm[0][t], pm[1][t]);
  __syncthreads();
  float acc = bm1[t];
#pragma unroll 8
  for (int k = 0; k < 640; ++k) acc = fmaf(feats[k], Wm1[(size_t)k * 128 + t], acc);
  hid[t] = acc > 0.f ? acc : 0.f;
  __syncthreads();
  if (t < 2) {
    float a = bm2[t];
    for (int j = 0; j < 128; ++j) a = fmaf(hid[j], Wm2[j * 2 + t], a);
    out[g * 2 + t] = a;
  }
}

// ---------------- launch ----------------

extern "C" void kernel_launch(void* const* d_in, const int* in_sizes, int n_in,
                              void* d_out, int out_size, void* d_ws, size_t ws_size,
                              hipStream_t stream) {
  const float* x   = (const float*)d_in[0];
  const float* emb = (const float*)d_in[1];
  const float* W1  = (const float*)d_in[2];
  const float* b1  = (const float*)d_in[3];
  const float* W2  = (const float*)d_in[4];
  const float* b2  = (const float*)d_in[5];
  const float* Wm1 = (const float*)d_in[6];
  const float* bm1 = (const float*)d_in[7];
  const float* Wm2 = (const float*)d_in[8];
  const float* bm2 = (const float*)d_in[9];
  const int* eidx  = (const int*)d_in[10];
  const int* drnl  = (const int*)d_in[11];
  const int* tloc  = (const int*)d_in[13];
  const int* ptr   = (const int*)d_in[14];
  float* out = (float*)d_out;

  const int N = in_sizes[11];
  const int E = in_sizes[10] / 2;
  const int G = in_sizes[13] / 2;
  const int NPG = N / G;
  const int* srcp = eidx;
  const int* dstp = eidx + E;

  char* w = (char*)d_ws;
  size_t o = 0;
  auto alloc = [&](size_t bytes) {
    void* p = w + o;
    o = align_up(o + bytes, 256);
    return p;
  };
  int*   rowptr = (int*)alloc((size_t)(N + 1) * 4);
  float* dinv   = (float*)alloc((size_t)N * 4);
  int*   bcnt   = (int*)alloc(NBUCK * 4);
  int*   esrc   = (int*)alloc((size_t)E * 4);
  unsigned short* hwb  = (unsigned short*)alloc((size_t)N * 128 * 2);  // bf16 [N][128]
  unsigned short* zb1  = (unsigned short*)alloc((size_t)N * 128 * 2);  // bf16 z layer1
  unsigned short* zb2  = (unsigned short*)alloc((size_t)N * 128 * 2);  // bf16 z layer2
  unsigned* staging = (unsigned*)zb2;  // 16.8MB overlay; used only before gemm1
  unsigned short* w1hi = (unsigned short*)alloc((size_t)160 * 128 * 2);
  unsigned short* w1lo = (unsigned short*)alloc((size_t)160 * 128 * 2);
  unsigned short* w2hi = (unsigned short*)alloc((size_t)128 * 128 * 2);
  unsigned short* w2lo = (unsigned short*)alloc((size_t)128 * 128 * 2);

  const int nch = (E + 4095) / 4096;
  const int nwsp = (160 * 128 + 128 * 128 + 255) / 256;
  const int nbk = (N + 255) / 256;

  hipMemsetAsync(bcnt, 0, NBUCK * 4, stream);
  bin_kernel<<<nch + nwsp, 256, 0, stream>>>(srcp, dstp, bcnt, staging, E, nch,
                                             W1, W2, w1hi, w1lo, w2hi, w2lo);
  csr_kernel<<<nbk, 256, 0, stream>>>(staging, bcnt, rowptr, dinv, esrc, N, E);

  gemm_mfma_kernel<<<(N + 127) / 128, 512, 0, stream>>>(x, emb, drnl, w1hi, w1lo, hwb, N);
  agg_kernel<<<(N * 64 + 255) / 256, 256, 0, stream>>>((const unsigned*)hwb, rowptr, esrc,
                                                       dinv, b1, (unsigned*)zb1, N);
  gemm_bf16a_kernel<<<(N + 127) / 128, 512, 0, stream>>>(zb1, w2hi, w2lo, hwb, N);
  agg_kernel<<<(N * 64 + 255) / 256, 256, 0, stream>>>((const unsigned*)hwb, rowptr, esrc,
                                                       dinv, b2, (unsigned*)zb2, N);
  final_kernel<<<G, 128, 0, stream>>>(zb2, tloc, ptr, Wm1, bm1, Wm2, bm2, out, NPG);
}